// Round 10
// baseline (34.499 us; speedup 1.0000x reference)
//
#include <hip/hip_runtime.h>
#include <hip/hip_fp16.h>

#define NPTS 16384
#define NBATCH 256
constexpr int THREADS = 1024;            // 16 waves; one block per row/CU
constexpr int NW      = THREADS / 64;    // 16 waves
constexpr int VSTRIDE = 25;              // 24 half2 payload + 1 pad (bank-spread)
// wave w owns points [w*1024,(w+1)*1024); lane i owns 4-pt mini-segments at
// w*1024 + g*256 + i*4 (g=0..3) -> every global load is 64x16B contiguous.
// Per-point wave-local prefixes go to LDS as fp16 so the streaming loop
// keeps ~30 live VGPRs and the compiler can pipeline the loads.

__device__ __forceinline__ float4 ld4(const float* p) {
  return *reinterpret_cast<const float4*>(p);
}

__global__ __launch_bounds__(THREADS, 4) void row_loss_kernel(
    const float* __restrict__ o3, const float* __restrict__ s3,
    const float* __restrict__ o2, const float* __restrict__ s2,
    const float* __restrict__ df, float* __restrict__ out) {
  const int b = blockIdx.x;
  const int t = threadIdx.x;
  const int lane = t & 63;
  const int wave = t >> 6;

  __shared__ __half2 vlds[THREADS * VSTRIDE];   // 100 KB
  __shared__ float wtot[3][NW];
  __shared__ float redbuf[NW];

  const float* r3p = s3 + (size_t)b * 3 * NPTS;
  const float* t3p = r3p + NPTS;
  const float* p3p = r3p + 2 * NPTS;
  const float* r2p = s2 + (size_t)b * 3 * NPTS;
  const float* t2p = r2p + NPTS;
  const float* p2p = r2p + 2 * NPTS;
  const float* dtp = df + (size_t)b * 2 * NPTS;
  const float* dpp = dtp + NPTS;

  const int wbase = wave * 1024;
  __half2* vt = vlds + t * VSTRIDE;

  // ---- Phase 1: stream, trig, wave-local prefix -> LDS (fp16) ----
  float runx = 0.f, runy = 0.f, runz = 0.f;   // wave-running total
  #pragma unroll
  for (int g = 0; g < 4; ++g) {
    const int idx = wbase + g * 256 + lane * 4;
    float4 R3 = ld4(r3p + idx), T3 = ld4(t3p + idx);
    float4 P3 = ld4(p3p + idx), R2 = ld4(r2p + idx);
    float4 T2 = ld4(t2p + idx), P2 = ld4(p2p + idx);
    float4 DT = ld4(dtp + idx), DP = ld4(dpp + idx);

    float vx[4], vy[4], vz[4];   // inclusive prefix within mini-segment
    float sx = 0.f, sy = 0.f, sz = 0.f;
    #pragma unroll
    for (int k = 0; k < 4; ++k) {
      float r3v = ((const float*)&R3)[k];
      float th3 = ((const float*)&T3)[k] + ((const float*)&DT)[k];
      float ph3 = ((const float*)&P3)[k] + ((const float*)&DP)[k];
      float r2v = ((const float*)&R2)[k];
      float th2 = ((const float*)&T2)[k];
      float ph2 = ((const float*)&P2)[k];
      float st3 = __sinf(th3), ct3 = __cosf(th3);
      float sp3 = __sinf(ph3), cp3 = __cosf(ph3);
      float st2 = __sinf(th2), ct2 = __cosf(th2);
      float sp2 = __sinf(ph2), cp2 = __cosf(ph2);
      sx += r3v * st3 * cp3 - r2v * st2 * cp2; vx[k] = sx;
      sy += r3v * st3 * sp3 - r2v * st2 * sp2; vy[k] = sy;
      sz += r3v * ct3 - r2v * ct2;             vz[k] = sz;
    }

    // wave scan of mini-segment totals (j-order: g-major, then lane)
    float ix = sx, iy = sy, iz = sz;
    #pragma unroll
    for (int off = 1; off < 64; off <<= 1) {
      float ax = __shfl_up(ix, off, 64);
      float ay = __shfl_up(iy, off, 64);
      float az = __shfl_up(iz, off, 64);
      if (lane >= off) { ix += ax; iy += ay; iz += az; }
    }
    const float sgx = runx + ix - sx;   // exclusive offset of this mini-seg
    const float sgy = runy + iy - sy;
    const float sgz = runz + iz - sz;
    runx += __shfl(ix, 63, 64);
    runy += __shfl(iy, 63, 64);
    runz += __shfl(iz, 63, 64);

    // per-point wave-local value v = seg offset + in-seg prefix -> fp16 LDS
    vt[g * 6 + 0] = __float22half2_rn(make_float2(sgx + vx[0], sgx + vx[1]));
    vt[g * 6 + 1] = __float22half2_rn(make_float2(sgx + vx[2], sgx + vx[3]));
    vt[g * 6 + 2] = __float22half2_rn(make_float2(sgy + vy[0], sgy + vy[1]));
    vt[g * 6 + 3] = __float22half2_rn(make_float2(sgy + vy[2], sgy + vy[3]));
    vt[g * 6 + 4] = __float22half2_rn(make_float2(sgz + vz[0], sgz + vz[1]));
    vt[g * 6 + 5] = __float22half2_rn(make_float2(sgz + vz[2], sgz + vz[3]));
  }

  if (lane == 0) { wtot[0][wave] = runx; wtot[1][wave] = runy; wtot[2][wave] = runz; }
  __syncthreads();

  // ---- Phase 2: block offset for this wave + row carry ----
  float wx = 0.f, wy = 0.f, wz = 0.f;
  #pragma unroll
  for (int w = 0; w < NW; ++w) {
    if (w < wave) { wx += wtot[0][w]; wy += wtot[1][w]; wz += wtot[2][w]; }
  }
  const float ox = o3[b * 3 + 0] - o2[b * 3 + 0];
  const float oy = o3[b * 3 + 1] - o2[b * 3 + 1];
  const float oz = o3[b * 3 + 2] - o2[b * 3 + 2];
  const float Bx = ox + wx, By = oy + wy, Bz = oz + wz;

  // ---- Phase 3: read back own prefixes, abs-sum ----
  float acc = 0.f;
  #pragma unroll
  for (int g = 0; g < 4; ++g) {
    float2 a;
    a = __half22float2(vt[g * 6 + 0]); acc += fabsf(Bx + a.x) + fabsf(Bx + a.y);
    a = __half22float2(vt[g * 6 + 1]); acc += fabsf(Bx + a.x) + fabsf(Bx + a.y);
    a = __half22float2(vt[g * 6 + 2]); acc += fabsf(By + a.x) + fabsf(By + a.y);
    a = __half22float2(vt[g * 6 + 3]); acc += fabsf(By + a.x) + fabsf(By + a.y);
    a = __half22float2(vt[g * 6 + 4]); acc += fabsf(Bz + a.x) + fabsf(Bz + a.y);
    a = __half22float2(vt[g * 6 + 5]); acc += fabsf(Bz + a.x) + fabsf(Bz + a.y);
  }
  if (t == 0) acc += fabsf(ox) + fabsf(oy) + fabsf(oz);  // j=0 cumsum term

  // ---- block reduction + one atomic per row ----
  #pragma unroll
  for (int off = 32; off > 0; off >>= 1) acc += __shfl_down(acc, off, 64);
  if (lane == 0) redbuf[wave] = acc;
  __syncthreads();
  if (t == 0) {
    float s = 0.f;
    #pragma unroll
    for (int w = 0; w < NW; ++w) s += redbuf[w];
    atomicAdd(out, s * (1.0f / (float)(NPTS + 1)));
  }
}

extern "C" void kernel_launch(void* const* d_in, const int* in_sizes, int n_in,
                              void* d_out, int out_size, void* d_ws, size_t ws_size,
                              hipStream_t stream) {
  const float* o3 = (const float*)d_in[0];  // origin_3D      (B,3,1)
  const float* s3 = (const float*)d_in[1];  // spherical_3D   (B,3,N)
  const float* o2 = (const float*)d_in[2];  // origin_2D      (B,3,1)
  const float* s2 = (const float*)d_in[3];  // spherical_2D   (B,3,N)
  const float* df = (const float*)d_in[4];  // deformation    (B,2,N)
  float* out = (float*)d_out;

  // out accumulates via atomicAdd; harness doesn't re-zero between replays.
  hipMemsetAsync(out, 0, sizeof(float) * out_size, stream);
  row_loss_kernel<<<NBATCH, THREADS, 0, stream>>>(o3, s3, o2, s2, df, out);
}